// Round 6
// baseline (2474.757 us; speedup 1.0000x reference)
//
#include <hip/hip_runtime.h>

// Problem constants
#define NN 2048
#define DD 128
#define KK 16
#define TT 16
#define EE 8192
#define TWOE 16384
#define CNT 262144.0f   // T * 2E

#define LOG2E 1.4426950408889634f
#define LN2   0.6931471805599453f

__device__ __forceinline__ float exp2_(float x) { return __builtin_amdgcn_exp2f(x); }
__device__ __forceinline__ float log2_(float x) { return __builtin_amdgcn_logf(x); }
__device__ __forceinline__ float expf_(float x) { return exp2_(x * LOG2E); }
__device__ __forceinline__ float logf_(float x) { return log2_(x) * LN2; }
__device__ __forceinline__ float sigmoidf_(float x) { return 1.f / (1.f + expf_(-x)); }
__device__ __forceinline__ float softplusf_(float x) { return fmaxf(x, 0.f) + logf_(1.f + expf_(-fabsf(x))); }
__device__ __forceinline__ float tanhf_(float x) { return 1.f - 2.f / (1.f + expf_(2.f * x)); }

#define D4(a,b) ((a).x*(b).x + (a).y*(b).y + (a).z*(b).z + (a).w*(b).w)

// ---------------------------------------------------------------------------
// init: prep concat weights + zero h/acc + alpha kld.
// ---------------------------------------------------------------------------
__launch_bounds__(256)
__global__ void init_kernel(const float* __restrict__ Wih_n, const float* __restrict__ Whh_n,
                            const float* __restrict__ Wih_c, const float* __restrict__ Whh_c,
                            const float* __restrict__ W_pmean, const float* __restrict__ W_pstd,
                            const float* __restrict__ W_bmean, const float* __restrict__ W_bstd,
                            float* __restrict__ Bg_n, float* __restrict__ Bg_c,
                            float* __restrict__ Bms_n, float* __restrict__ Bms_c,
                            float* __restrict__ hphiA, float* __restrict__ hbetaA,
                            const float* __restrict__ amE, const float* __restrict__ asE,
                            const int* __restrict__ sidx, float* __restrict__ acc)
{
    if (blockIdx.x == 1024) {
        __shared__ float red[128];
        int d = threadIdx.x;
        if (d < 128) {
            int s = sidx[0];
            float am = amE[s*128 + d];
            float as = softplusf_(asE[s*128 + d]);
            red[d] = -logf_(as) + 0.5f*(as*as + am*am) - 0.5f;
        }
        __syncthreads();
        for (int st = 64; st > 0; st >>= 1) { if (d < st && d + st < 128) red[d] += red[d + st]; __syncthreads(); }
        if (d == 0) acc[2] = red[0];
        return;
    }
    int idx = blockIdx.x * 256 + threadIdx.x;   // < 262144
    hphiA[idx] = 0.f;
    if (idx < 2048) hbetaA[idx] = 0.f;
    if (idx < 2) { acc[idx] = 0.f; acc[idx + 3] = 0.f; }
    if (idx < 98304) {
        int r = idx;
        if (r < 49152) { int j = r >> 7, k2 = r & 127; Bg_n[r] = Wih_n[j*256 + k2] + Wih_n[j*256 + 128 + k2]; }
        else Bg_n[r] = Whh_n[r - 49152];
    } else if (idx < 196608) {
        int r = idx - 98304;
        if (r < 49152) { int j = r >> 7, k2 = r & 127; Bg_c[r] = Wih_c[j*256 + k2] + Wih_c[j*256 + 128 + k2]; }
        else Bg_c[r] = Whh_c[r - 49152];
    } else if (idx < 229376) {
        int r = idx - 196608;
        Bms_n[r] = (r < 16384) ? W_pmean[r] : W_pstd[r - 16384];
    } else {
        int r = idx - 229376;
        Bms_c[r] = (r < 16384) ? W_bmean[r] : W_bstd[r - 16384];
    }
}

// ---------------------------------------------------------------------------
// phi0/beta0 GEMV (reads amE directly; no init dependency)
// ---------------------------------------------------------------------------
__launch_bounds__(256)
__global__ void phi0_kernel(const float* __restrict__ Wp, const float* __restrict__ bp,
                            const float* __restrict__ Wb, const float* __restrict__ bb,
                            const float* __restrict__ amE, const int* __restrict__ sidx,
                            float* __restrict__ phi0, float* __restrict__ beta0)
{
    int wid = threadIdx.x >> 6, l = threadIdx.x & 63;
    int s = sidx[0];
    long long row = (long long)blockIdx.x * 4 + wid;     // < 264192
    const float* W; const float* b; float* o; long long r = row;
    if (row < 262144) { W = Wp; b = bp; o = phi0; }
    else { W = Wb; b = bb; o = beta0; r = row - 262144; }
    const float* wr = W + r * 128;
    float acc = amE[s*128 + l] * wr[l] + amE[s*128 + 64 + l] * wr[64 + l];
    #pragma unroll
    for (int m = 32; m >= 1; m >>= 1) acc += __shfl_xor(acc, m);
    if (l == 0) o[r] = acc + b[r];
}

// ---------------------------------------------------------------------------
// Fused GRU (unchanged from round 5)
// ---------------------------------------------------------------------------
__launch_bounds__(256)
__global__ void gru_kernel(const float* __restrict__ phiPrior, const float* __restrict__ betaPrior,
                           const float* __restrict__ hPhiOld, float* __restrict__ hPhiNew,
                           const float* __restrict__ hBetaOld, float* __restrict__ hBetaNew,
                           const float* __restrict__ Bg_n, const float* __restrict__ Bg_c,
                           const float* __restrict__ bih_n, const float* __restrict__ bhh_n,
                           const float* __restrict__ bih_c, const float* __restrict__ bhh_c)
{
    __shared__ float Xs[32][64];
    __shared__ float Hs[32][64];
    __shared__ float Ws[32][192];
    int bx = blockIdx.x;
    const float* X; const float* Hold; float* Hnew; const float* Bg; const float* bih; const float* bhh;
    int m0, M, j0;
    if (bx < 128) {
        m0 = (bx >> 2) * 64; j0 = (bx & 3) * 32; M = 2048;
        X = phiPrior; Hold = hPhiOld; Hnew = hPhiNew; Bg = Bg_n; bih = bih_n; bhh = bhh_n;
    } else {
        m0 = 0; j0 = (bx - 128) * 32; M = 16;
        X = betaPrior; Hold = hBetaOld; Hnew = hBetaNew; Bg = Bg_c; bih = bih_c; bhh = bhh_c;
    }
    int tid = threadIdx.x;
    int j  = tid & 31;
    int rr = tid >> 5;            // 0..7 -> rows rr*8..rr*8+7
    float acc[6][8] = {};
    int srow = tid >> 3;          // 0..31
    int skq  = (tid & 7) * 4;
    for (int k0 = 0; k0 < 128; k0 += 32) {
        #pragma unroll
        for (int h2 = 0; h2 < 2; ++h2) {
            int row = srow + 32 * h2;
            int grow = m0 + row;
            float4 xv = make_float4(0.f,0.f,0.f,0.f), hv = xv;
            if (grow < M) {
                xv = *(const float4*)(X    + (size_t)grow*128 + k0 + skq);
                hv = *(const float4*)(Hold + (size_t)grow*128 + k0 + skq);
            }
            Xs[skq+0][row] = xv.x; Xs[skq+1][row] = xv.y; Xs[skq+2][row] = xv.z; Xs[skq+3][row] = xv.w;
            Hs[skq+0][row] = hv.x; Hs[skq+1][row] = hv.y; Hs[skq+2][row] = hv.z; Hs[skq+3][row] = hv.w;
        }
        #pragma unroll
        for (int h6 = 0; h6 < 6; ++h6) {
            int rowIdx = srow + 32 * h6;          // 0..191
            int g = rowIdx >> 5, jj2 = rowIdx & 31;
            float4 wv = *(const float4*)(Bg + (size_t)(g*128 + j0 + jj2)*128 + k0 + skq);
            Ws[skq+0][rowIdx] = wv.x; Ws[skq+1][rowIdx] = wv.y; Ws[skq+2][rowIdx] = wv.z; Ws[skq+3][rowIdx] = wv.w;
        }
        __syncthreads();
        #pragma unroll
        for (int kk = 0; kk < 32; ++kk) {
            float xa[8], ha[8];
            *(float4*)&xa[0] = *(const float4*)&Xs[kk][rr*8];
            *(float4*)&xa[4] = *(const float4*)&Xs[kk][rr*8+4];
            *(float4*)&ha[0] = *(const float4*)&Hs[kk][rr*8];
            *(float4*)&ha[4] = *(const float4*)&Hs[kk][rr*8+4];
            #pragma unroll
            for (int g = 0; g < 3; ++g) {
                float wv = Ws[kk][g*32 + j];
                #pragma unroll
                for (int i = 0; i < 8; ++i) acc[g][i] = fmaf(xa[i], wv, acc[g][i]);
            }
            #pragma unroll
            for (int g = 3; g < 6; ++g) {
                float wv = Ws[kk][g*32 + j];
                #pragma unroll
                for (int i = 0; i < 8; ++i) acc[g][i] = fmaf(ha[i], wv, acc[g][i]);
            }
        }
        __syncthreads();
    }
    float bi_r = bih[j0 + j], bi_z = bih[128 + j0 + j], bi_n = bih[256 + j0 + j];
    float bh_r = bhh[j0 + j], bh_z = bhh[128 + j0 + j], bh_n = bhh[256 + j0 + j];
    #pragma unroll
    for (int i = 0; i < 8; ++i) {
        int row = m0 + rr*8 + i;
        if (row < M) {
            float r_ = sigmoidf_(acc[0][i] + bi_r + acc[3][i] + bh_r);
            float z_ = sigmoidf_(acc[1][i] + bi_z + acc[4][i] + bh_z);
            float n_ = tanhf_(acc[2][i] + bi_n + r_ * (acc[5][i] + bh_n));
            size_t hi = (size_t)row * 128 + j0 + j;
            Hnew[hi] = (1.f - z_) * n_ + z_ * Hold[hi];
        }
    }
}

// ---------------------------------------------------------------------------
// Fused mean/std+sample+KLD (phi) AND beta+Mt:
//  bx<128: phi ms path (64 rows x 32 j).
//  bx 128..159: recompute full beta ms locally in LDS (16x256, cheap), then
//               compute Mt rows (bx-128)*64..+64. bx==128 also writes betaS
//               global + kld_beta.
// ---------------------------------------------------------------------------
__launch_bounds__(256)
__global__ void msmt_kernel(const float* __restrict__ hPhi, const float* __restrict__ hBeta,
                            const float* __restrict__ Bms_n, const float* __restrict__ Bms_c,
                            const float* __restrict__ b_pmean, const float* __restrict__ b_pstd,
                            const float* __restrict__ b_bmean, const float* __restrict__ b_bstd,
                            const float* __restrict__ epsP, const float* __restrict__ epsB,
                            const float* __restrict__ phiPrior, const float* __restrict__ betaPrior,
                            float* __restrict__ phiS, float* __restrict__ betaS,
                            const float* __restrict__ W_dec, float* __restrict__ Mt,
                            float* __restrict__ acc)
{
    __shared__ float red[256];
    int bx = blockIdx.x;
    int tid = threadIdx.x;
    if (bx < 128) {
        __shared__ float Hs[32][64];
        __shared__ float Wms[32][64];
        int m0 = (bx >> 2) * 64, j0 = (bx & 3) * 32;
        int j  = tid & 31;
        int rr = tid >> 5;
        float accM[8] = {}, accS[8] = {};
        int srow = tid >> 3;
        int skq  = (tid & 7) * 4;
        for (int k0 = 0; k0 < 128; k0 += 32) {
            #pragma unroll
            for (int h2 = 0; h2 < 2; ++h2) {
                int row = srow + 32 * h2;
                float4 hv = *(const float4*)(hPhi + (size_t)(m0 + row)*128 + k0 + skq);
                Hs[skq+0][row] = hv.x; Hs[skq+1][row] = hv.y; Hs[skq+2][row] = hv.z; Hs[skq+3][row] = hv.w;
            }
            #pragma unroll
            for (int h2 = 0; h2 < 2; ++h2) {
                int ri = srow + 32 * h2;            // 0..63: mean rows then std rows
                int grp = ri >> 5, jj2 = ri & 31;
                float4 wv = *(const float4*)(Bms_n + (size_t)(grp*128 + j0 + jj2)*128 + k0 + skq);
                Wms[skq+0][ri] = wv.x; Wms[skq+1][ri] = wv.y; Wms[skq+2][ri] = wv.z; Wms[skq+3][ri] = wv.w;
            }
            __syncthreads();
            #pragma unroll
            for (int kk = 0; kk < 32; ++kk) {
                float hv[8];
                *(float4*)&hv[0] = *(const float4*)&Hs[kk][rr*8];
                *(float4*)&hv[4] = *(const float4*)&Hs[kk][rr*8+4];
                float wm = Wms[kk][j];
                float wsv = Wms[kk][32 + j];
                #pragma unroll
                for (int i = 0; i < 8; ++i) {
                    accM[i] = fmaf(hv[i], wm, accM[i]);
                    accS[i] = fmaf(hv[i], wsv, accS[i]);
                }
            }
            __syncthreads();
        }
        float bmv = b_pmean[j0 + j], bsv = b_pstd[j0 + j];
        float kld = 0.f;
        #pragma unroll
        for (int i = 0; i < 8; ++i) {
            int row = m0 + rr*8 + i;
            size_t gi = (size_t)row * 128 + j0 + j;
            float mean = accM[i] + bmv;
            float stdv = softplusf_(accS[i] + bsv);
            phiS[gi] = mean + stdv * epsP[gi];
            float d = mean - phiPrior[gi];
            kld += -logf_(stdv) + 0.5f*(stdv*stdv + d*d) - 0.5f;
        }
        red[tid] = kld; __syncthreads();
        for (int st = 128; st > 0; st >>= 1) { if (tid < st) red[tid] += red[tid + st]; __syncthreads(); }
        if (tid == 0) atomicAdd(acc + 4, red[0]);
    } else {
        __shared__ float hb[2048];        // h_beta 16x128
        __shared__ float sbeta[16*132];   // padded beta_s
        int bm = bx - 128;                // 0..31
        // stage h_beta
        {
            int base = tid * 8;
            *(float4*)&hb[base]     = *(const float4*)(hBeta + base);
            *(float4*)&hb[base + 4] = *(const float4*)(hBeta + base + 4);
        }
        __syncthreads();
        // beta ms: thread (j = tid&127, half = tid>>7) -> 8 rows
        {
            int j = tid & 127, half = tid >> 7;
            float accM[8] = {}, accS[8] = {};
            const float* wmrow = Bms_c + (size_t)j * 128;
            const float* wsrow = Bms_c + (size_t)(128 + j) * 128;
            for (int d4 = 0; d4 < 32; ++d4) {
                float4 wm = *(const float4*)(wmrow + d4*4);
                float4 wsv = *(const float4*)(wsrow + d4*4);
                #pragma unroll
                for (int i = 0; i < 8; ++i) {
                    int r = half*8 + i;
                    float4 hv = *(const float4*)&hb[r*128 + d4*4];
                    accM[i] += D4(hv, wm);
                    accS[i] += D4(hv, wsv);
                }
            }
            float bmv = b_bmean[j], bsv = b_bstd[j];
            float kld = 0.f;
            #pragma unroll
            for (int i = 0; i < 8; ++i) {
                int r = half*8 + i;
                float mean = accM[i] + bmv;
                float stdv = softplusf_(accS[i] + bsv);
                float sv = mean + stdv * epsB[r*128 + j];
                sbeta[r*132 + j] = sv;
                if (bm == 0) {
                    betaS[r*128 + j] = sv;
                    float d = mean - betaPrior[r*128 + j];
                    kld += (-2.3025850929940457f - logf_(stdv)) + 50.0f*(stdv*stdv + d*d) - 0.5f;
                }
            }
            if (bm == 0) {
                red[tid] = kld; __syncthreads();
                for (int st = 128; st > 0; st >>= 1) { if (tid < st) red[tid] += red[tid + st]; __syncthreads(); }
                if (tid == 0) atomicAdd(acc + 3, red[0]);
            }
        }
        __syncthreads();
        // Mt rows bm*64 .. +64: wave w handles 16 rows, lane (k=l&15, q=l>>4)
        {
            int w = tid >> 6, l = tid & 63;
            int k = l & 15, q = l >> 4;
            const float* sb = &sbeta[k*132 + q*32];
            #pragma unroll 4
            for (int rr2 = 0; rr2 < 16; ++rr2) {
                int n = bm*64 + w*16 + rr2;
                const float* wd = W_dec + (size_t)n*128 + q*32;
                float p = 0.f;
                #pragma unroll
                for (int i4 = 0; i4 < 8; ++i4) {
                    float4 a = *(const float4*)(sb + i4*4);
                    float4 b = *(const float4*)(wd + i4*4);
                    p += D4(a, b);
                }
                p += __shfl_xor(p, 16);
                p += __shfl_xor(p, 32);
                if (l < 16) Mt[n*16 + l] = p * LOG2E;
            }
        }
    }
}

// ---------------------------------------------------------------------------
// Fused z + nll v3. 512 blocks x 512 thr, 32 edges/block.
// Phase 1: 8 waves x 4 edges; per-lane kz accumulation (one butterfly, x0.25).
// Phase 2: Mt register-resident; per-edge s butterfly only; cv accumulated
// locally by owner thread (one butterfly at end).
// ---------------------------------------------------------------------------
#define ZSTEP(A,B,Wv,Bv) { float4 a_=(A), b_=(B); \
    lp += a_.x*(Bv).x + a_.y*(Bv).y + a_.z*(Bv).z + a_.w*(Bv).w; \
    lq += (a_.x*b_.x)*(Wv).x + (a_.y*b_.y)*(Wv).y + (a_.z*b_.z)*(Wv).z + (a_.w*b_.w)*(Wv).w; }

__launch_bounds__(512, 4)
__global__ void znll_kernel(const float* __restrict__ phiS, const float* __restrict__ betaS,
                            const float* __restrict__ W_pi, const float* __restrict__ Mt,
                            const int* __restrict__ edges_t, const float* __restrict__ u_t,
                            float* __restrict__ acc)
{
    __shared__ float zbuf[32][16];
    __shared__ int   cbuf[32];
    __shared__ float ss[32][8];
    __shared__ float kred[8], cvred[8];
    int tid = threadIdx.x, wid = tid >> 6, l = tid & 63;
    // ---- phase 1 ----
    {
        int k = l >> 2, q = l & 3;
        int d0 = q * 32;
        const float4* wp = (const float4*)(W_pi  + k*128 + d0);
        const float4* bp = (const float4*)(betaS + k*128 + d0);
        float4 wr0 = wp[0], wr1 = wp[1], wr2 = wp[2], wr3 = wp[3],
               wr4 = wp[4], wr5 = wp[5], wr6 = wp[6], wr7 = wp[7];
        float4 br0 = bp[0], br1 = bp[1], br2 = bp[2], br3 = bp[3],
               br4 = bp[4], br5 = bp[5], br6 = bp[6], br7 = bp[7];
        float kz = 0.f;
        #pragma unroll
        for (int it = 0; it < 4; ++it) {
            int jl = wid * 4 + it;               // 0..31
            int j = blockIdx.x * 32 + jl;        // 0..16383
            int e = j & 8191; int fl = j >> 13;
            int w = edges_t[e*2 + fl], c = edges_t[e*2 + (fl ^ 1)];
            const float4* pw4 = (const float4*)(phiS + (size_t)w*128 + d0);
            const float4* pc4 = (const float4*)(phiS + (size_t)c*128 + d0);
            float lq = 0.f, lp = 0.f;
            ZSTEP(pw4[0], pc4[0], wr0, br0); ZSTEP(pw4[1], pc4[1], wr1, br1);
            ZSTEP(pw4[2], pc4[2], wr2, br2); ZSTEP(pw4[3], pc4[3], wr3, br3);
            ZSTEP(pw4[4], pc4[4], wr4, br4); ZSTEP(pw4[5], pc4[5], wr5, br5);
            ZSTEP(pw4[6], pc4[6], wr6, br6); ZSTEP(pw4[7], pc4[7], wr7, br7);
            lq += __shfl_xor(lq, 1); lq += __shfl_xor(lq, 2);
            lp += __shfl_xor(lp, 1); lp += __shfl_xor(lp, 2);
            // posterior log-softmax (no max: |lq| bounded)
            float eq = expf_(lq);
            float sq = eq;
            sq += __shfl_xor(sq, 4); sq += __shfl_xor(sq, 8); sq += __shfl_xor(sq, 16); sq += __shfl_xor(sq, 32);
            float logpost = lq - logf_(sq);
            float post = eq * __builtin_amdgcn_rcpf(sq);
            // prior log-softmax (keep max)
            float mp = lp;
            mp = fmaxf(mp, __shfl_xor(mp, 4));  mp = fmaxf(mp, __shfl_xor(mp, 8));
            mp = fmaxf(mp, __shfl_xor(mp, 16)); mp = fmaxf(mp, __shfl_xor(mp, 32));
            float ep = expf_(lp - mp);
            float sp = ep;
            sp += __shfl_xor(sp, 4); sp += __shfl_xor(sp, 8); sp += __shfl_xor(sp, 16); sp += __shfl_xor(sp, 32);
            float logprior = (lp - mp) - logf_(sp);
            kz += post * (logpost - logprior);   // this lane's k only (x4 over q)
            // gumbel-softmax sample
            float u = u_t[(size_t)j*16 + k];
            float g = -logf_(-logf_(u + 1e-10f) + 1e-10f);
            float zl = lq + g;
            float ez = expf_(zl);
            float sz = ez;
            sz += __shfl_xor(sz, 4); sz += __shfl_xor(sz, 8); sz += __shfl_xor(sz, 16); sz += __shfl_xor(sz, 32);
            if (q == 0) zbuf[jl][k] = ez * __builtin_amdgcn_rcpf(sz);
            if (l == 0) cbuf[jl] = c;
        }
        #pragma unroll
        for (int m = 1; m < 64; m <<= 1) kz += __shfl_xor(kz, m);
        if (l == 0) kred[wid] = kz * 0.25f;
    }
    __syncthreads();
    // ---- phase 2 ----
    int n0 = tid * 4;
    const float4* mp4 = (const float4*)(Mt + (size_t)n0 * 16);
    float4 M0 = mp4[0],  M1 = mp4[1],  M2 = mp4[2],  M3 = mp4[3];
    float4 M4 = mp4[4],  M5 = mp4[5],  M6 = mp4[6],  M7 = mp4[7];
    float4 M8 = mp4[8],  M9 = mp4[9],  M10 = mp4[10], M11 = mp4[11];
    float4 M12 = mp4[12], M13 = mp4[13], M14 = mp4[14], M15 = mp4[15];
    float cvsum = 0.f;
    #pragma unroll 2
    for (int e = 0; e < 32; ++e) {
        const float4* zp = (const float4*)&zbuf[e][0];
        float4 Z0 = zp[0], Z1 = zp[1], Z2 = zp[2], Z3 = zp[3];
        int c = cbuf[e];
        float v0 = D4(Z0, M0)  + D4(Z1, M1)  + D4(Z2, M2)  + D4(Z3, M3);
        float v1 = D4(Z0, M4)  + D4(Z1, M5)  + D4(Z2, M6)  + D4(Z3, M7);
        float v2 = D4(Z0, M8)  + D4(Z1, M9)  + D4(Z2, M10) + D4(Z3, M11);
        float v3 = D4(Z0, M12) + D4(Z1, M13) + D4(Z2, M14) + D4(Z3, M15);
        float s = exp2_(v0) + exp2_(v1) + exp2_(v2) + exp2_(v3);
        cvsum += (c == n0) ? v0 : 0.f;
        cvsum += (c == n0 + 1) ? v1 : 0.f;
        cvsum += (c == n0 + 2) ? v2 : 0.f;
        cvsum += (c == n0 + 3) ? v3 : 0.f;
        #pragma unroll
        for (int m = 1; m < 64; m <<= 1) s += __shfl_xor(s, m);
        if (l == 0) ss[e][wid] = s;
    }
    #pragma unroll
    for (int m = 1; m < 64; m <<= 1) cvsum += __shfl_xor(cvsum, m);
    if (l == 0) cvred[wid] = cvsum;
    __syncthreads();
    if (wid == 0) {
        float val = 0.f;
        if (l < 32) {
            float S = 0.f;
            #pragma unroll
            for (int w2 = 0; w2 < 8; ++w2) S += ss[l][w2];
            val = log2_(S);
        }
        #pragma unroll
        for (int m = 1; m < 64; m <<= 1) val += __shfl_xor(val, m);
        if (l == 0) {
            float cvt = 0.f, kzt = 0.f;
            #pragma unroll
            for (int w2 = 0; w2 < 8; ++w2) { cvt += cvred[w2]; kzt += kred[w2]; }
            atomicAdd(acc + 0, LN2 * (val - cvt));
            atomicAdd(acc + 1, kzt);
        }
    }
}

__global__ void final_kernel(const float* __restrict__ acc, float* __restrict__ out)
{
    if (threadIdx.x == 0 && blockIdx.x == 0) {
        out[0] = acc[0] / CNT;
        out[1] = acc[1] / CNT;
        out[2] = 16.f * acc[2] / CNT;
        out[3] = acc[3] / CNT;
        out[4] = acc[4] / CNT;
    }
}

// ---------------------------------------------------------------------------
extern "C" void kernel_launch(void* const* d_in, const int* in_sizes, int n_in,
                              void* d_out, int out_size, void* d_ws, size_t ws_size,
                              hipStream_t stream)
{
    (void)in_sizes; (void)n_in; (void)out_size; (void)ws_size;
    const int*   edges   = (const int*)d_in[0];
    const int*   sidx    = (const int*)d_in[1];
    const float* eps_phi = (const float*)d_in[2];
    const float* eps_beta= (const float*)d_in[3];
    const float* u_g     = (const float*)d_in[4];
    const float* amE     = (const float*)d_in[5];
    const float* asE     = (const float*)d_in[6];
    const float* W_s2phi = (const float*)d_in[7];
    const float* b_s2phi = (const float*)d_in[8];
    const float* W_s2beta= (const float*)d_in[9];
    const float* b_s2beta= (const float*)d_in[10];
    const float* W_bmean = (const float*)d_in[11];
    const float* b_bmean = (const float*)d_in[12];
    const float* W_bstd  = (const float*)d_in[13];
    const float* b_bstd  = (const float*)d_in[14];
    const float* W_pmean = (const float*)d_in[15];
    const float* b_pmean = (const float*)d_in[16];
    const float* W_pstd  = (const float*)d_in[17];
    const float* b_pstd  = (const float*)d_in[18];
    const float* W_pi    = (const float*)d_in[19];
    const float* Wih_n   = (const float*)d_in[20];
    const float* Whh_n   = (const float*)d_in[21];
    const float* bih_n   = (const float*)d_in[22];
    const float* bhh_n   = (const float*)d_in[23];
    const float* Wih_c   = (const float*)d_in[24];
    const float* Whh_c   = (const float*)d_in[25];
    const float* bih_c   = (const float*)d_in[26];
    const float* bhh_c   = (const float*)d_in[27];
    const float* W_dec   = (const float*)d_in[28];

    float* ws     = (float*)d_ws;
    float* Bg_n   = ws;                    // 98304
    float* Bg_c   = Bg_n   + 98304;        // 98304
    float* Bms_n  = Bg_c   + 98304;        // 32768
    float* Bms_c  = Bms_n  + 32768;        // 32768
    float* phiA   = Bms_c  + 32768;        // 262144
    float* phiB   = phiA   + 262144;       // 262144
    float* hphiA  = phiB   + 262144;       // 262144
    float* hphiB  = hphiA  + 262144;       // 262144
    float* betaA  = hphiB  + 262144;       // 2048
    float* betaB  = betaA  + 2048;         // 2048
    float* hbetaA = betaB  + 2048;         // 2048
    float* hbetaB = hbetaA + 2048;         // 2048
    float* Mt     = hbetaB + 2048;         // 32768
    float* acc    = Mt     + 32768;        // 8

    init_kernel<<<1025, 256, 0, stream>>>(Wih_n, Whh_n, Wih_c, Whh_c,
                                          W_pmean, W_pstd, W_bmean, W_bstd,
                                          Bg_n, Bg_c, Bms_n, Bms_c,
                                          hphiA, hbetaA, amE, asE, sidx, acc);
    phi0_kernel<<<66048, 256, 0, stream>>>(W_s2phi, b_s2phi, W_s2beta, b_s2beta, amE, sidx, phiA, betaA);

    float* phiPrior = phiA;  float* phiS = phiB;
    float* betaPrior = betaA; float* betaS = betaB;
    float* hPhiOld = hphiA;  float* hPhiNew = hphiB;
    float* hBetaOld = hbetaA; float* hBetaNew = hbetaB;
    for (int t = 0; t < TT; ++t) {
        gru_kernel<<<132, 256, 0, stream>>>(phiPrior, betaPrior,
                                            hPhiOld, hPhiNew, hBetaOld, hBetaNew,
                                            Bg_n, Bg_c, bih_n, bhh_n, bih_c, bhh_c);
        msmt_kernel<<<160, 256, 0, stream>>>(hPhiNew, hBetaNew, Bms_n, Bms_c,
                                             b_pmean, b_pstd, b_bmean, b_bstd,
                                             eps_phi + (size_t)t * 262144, eps_beta + (size_t)t * 2048,
                                             phiPrior, betaPrior, phiS, betaS, W_dec, Mt, acc);
        znll_kernel<<<512, 512, 0, stream>>>(phiS, betaS, W_pi, Mt,
                                             edges + (size_t)t * EE * 2, u_g + (size_t)t * TWOE * KK, acc);
        float* tp = phiPrior; phiPrior = phiS; phiS = tp;
        float* tb = betaPrior; betaPrior = betaS; betaS = tb;
        float* th = hPhiOld; hPhiOld = hPhiNew; hPhiNew = th;
        float* tb2 = hBetaOld; hBetaOld = hBetaNew; hBetaNew = tb2;
    }
    final_kernel<<<1, 64, 0, stream>>>(acc, (float*)d_out);
}

// Round 7
// 2470.927 us; speedup vs baseline: 1.0015x; 1.0015x over previous
//
#include <hip/hip_runtime.h>

// Problem constants
#define NN 2048
#define DD 128
#define KK 16
#define TT 16
#define EE 8192
#define TWOE 16384
#define CNT 262144.0f   // T * 2E

#define LOG2E 1.4426950408889634f
#define LN2   0.6931471805599453f

__device__ __forceinline__ float exp2_(float x) { return __builtin_amdgcn_exp2f(x); }
__device__ __forceinline__ float log2_(float x) { return __builtin_amdgcn_logf(x); }
__device__ __forceinline__ float expf_(float x) { return exp2_(x * LOG2E); }
__device__ __forceinline__ float logf_(float x) { return log2_(x) * LN2; }
__device__ __forceinline__ float sigmoidf_(float x) { return 1.f / (1.f + expf_(-x)); }
__device__ __forceinline__ float softplusf_(float x) { return fmaxf(x, 0.f) + logf_(1.f + expf_(-fabsf(x))); }
__device__ __forceinline__ float tanhf_(float x) { return 1.f - 2.f / (1.f + expf_(2.f * x)); }

#define D4(a,b) ((a).x*(b).x + (a).y*(b).y + (a).z*(b).z + (a).w*(b).w)

// ---------------------------------------------------------------------------
// init: prep concat weights + zero h/acc + alpha kld.
// ---------------------------------------------------------------------------
__launch_bounds__(256)
__global__ void init_kernel(const float* __restrict__ Wih_n, const float* __restrict__ Whh_n,
                            const float* __restrict__ Wih_c, const float* __restrict__ Whh_c,
                            const float* __restrict__ W_pmean, const float* __restrict__ W_pstd,
                            const float* __restrict__ W_bmean, const float* __restrict__ W_bstd,
                            float* __restrict__ Bg_n, float* __restrict__ Bg_c,
                            float* __restrict__ Bms_n, float* __restrict__ Bms_c,
                            float* __restrict__ hphiA, float* __restrict__ hbetaA,
                            const float* __restrict__ amE, const float* __restrict__ asE,
                            const int* __restrict__ sidx, float* __restrict__ acc)
{
    if (blockIdx.x == 1024) {
        __shared__ float red[128];
        int d = threadIdx.x;
        if (d < 128) {
            int s = sidx[0];
            float am = amE[s*128 + d];
            float as = softplusf_(asE[s*128 + d]);
            red[d] = -logf_(as) + 0.5f*(as*as + am*am) - 0.5f;
        }
        __syncthreads();
        for (int st = 64; st > 0; st >>= 1) { if (d < st && d + st < 128) red[d] += red[d + st]; __syncthreads(); }
        if (d == 0) acc[2] = red[0];
        return;
    }
    int idx = blockIdx.x * 256 + threadIdx.x;   // < 262144
    hphiA[idx] = 0.f;
    if (idx < 2048) hbetaA[idx] = 0.f;
    if (idx < 2) { acc[idx] = 0.f; acc[idx + 3] = 0.f; }
    if (idx < 98304) {
        int r = idx;
        if (r < 49152) { int j = r >> 7, k2 = r & 127; Bg_n[r] = Wih_n[j*256 + k2] + Wih_n[j*256 + 128 + k2]; }
        else Bg_n[r] = Whh_n[r - 49152];
    } else if (idx < 196608) {
        int r = idx - 98304;
        if (r < 49152) { int j = r >> 7, k2 = r & 127; Bg_c[r] = Wih_c[j*256 + k2] + Wih_c[j*256 + 128 + k2]; }
        else Bg_c[r] = Whh_c[r - 49152];
    } else if (idx < 229376) {
        int r = idx - 196608;
        Bms_n[r] = (r < 16384) ? W_pmean[r] : W_pstd[r - 16384];
    } else {
        int r = idx - 229376;
        Bms_c[r] = (r < 16384) ? W_bmean[r] : W_bstd[r - 16384];
    }
}

// ---------------------------------------------------------------------------
// phi0/beta0 GEMV (reads amE directly; no init dependency)
// ---------------------------------------------------------------------------
__launch_bounds__(256)
__global__ void phi0_kernel(const float* __restrict__ Wp, const float* __restrict__ bp,
                            const float* __restrict__ Wb, const float* __restrict__ bb,
                            const float* __restrict__ amE, const int* __restrict__ sidx,
                            float* __restrict__ phi0, float* __restrict__ beta0)
{
    int wid = threadIdx.x >> 6, l = threadIdx.x & 63;
    int s = sidx[0];
    long long row = (long long)blockIdx.x * 4 + wid;     // < 264192
    const float* W; const float* b; float* o; long long r = row;
    if (row < 262144) { W = Wp; b = bp; o = phi0; }
    else { W = Wb; b = bb; o = beta0; r = row - 262144; }
    const float* wr = W + r * 128;
    float acc = amE[s*128 + l] * wr[l] + amE[s*128 + 64 + l] * wr[64 + l];
    #pragma unroll
    for (int m = 32; m >= 1; m >>= 1) acc += __shfl_xor(acc, m);
    if (l == 0) o[r] = acc + b[r];
}

// ---------------------------------------------------------------------------
// Fused GRU
// ---------------------------------------------------------------------------
__launch_bounds__(256)
__global__ void gru_kernel(const float* __restrict__ phiPrior, const float* __restrict__ betaPrior,
                           const float* __restrict__ hPhiOld, float* __restrict__ hPhiNew,
                           const float* __restrict__ hBetaOld, float* __restrict__ hBetaNew,
                           const float* __restrict__ Bg_n, const float* __restrict__ Bg_c,
                           const float* __restrict__ bih_n, const float* __restrict__ bhh_n,
                           const float* __restrict__ bih_c, const float* __restrict__ bhh_c)
{
    __shared__ float Xs[32][64];
    __shared__ float Hs[32][64];
    __shared__ float Ws[32][192];
    int bx = blockIdx.x;
    const float* X; const float* Hold; float* Hnew; const float* Bg; const float* bih; const float* bhh;
    int m0, M, j0;
    if (bx < 128) {
        m0 = (bx >> 2) * 64; j0 = (bx & 3) * 32; M = 2048;
        X = phiPrior; Hold = hPhiOld; Hnew = hPhiNew; Bg = Bg_n; bih = bih_n; bhh = bhh_n;
    } else {
        m0 = 0; j0 = (bx - 128) * 32; M = 16;
        X = betaPrior; Hold = hBetaOld; Hnew = hBetaNew; Bg = Bg_c; bih = bih_c; bhh = bhh_c;
    }
    int tid = threadIdx.x;
    int j  = tid & 31;
    int rr = tid >> 5;            // 0..7 -> rows rr*8..rr*8+7
    float acc[6][8] = {};
    int srow = tid >> 3;          // 0..31
    int skq  = (tid & 7) * 4;
    for (int k0 = 0; k0 < 128; k0 += 32) {
        #pragma unroll
        for (int h2 = 0; h2 < 2; ++h2) {
            int row = srow + 32 * h2;
            int grow = m0 + row;
            float4 xv = make_float4(0.f,0.f,0.f,0.f), hv = xv;
            if (grow < M) {
                xv = *(const float4*)(X    + (size_t)grow*128 + k0 + skq);
                hv = *(const float4*)(Hold + (size_t)grow*128 + k0 + skq);
            }
            Xs[skq+0][row] = xv.x; Xs[skq+1][row] = xv.y; Xs[skq+2][row] = xv.z; Xs[skq+3][row] = xv.w;
            Hs[skq+0][row] = hv.x; Hs[skq+1][row] = hv.y; Hs[skq+2][row] = hv.z; Hs[skq+3][row] = hv.w;
        }
        #pragma unroll
        for (int h6 = 0; h6 < 6; ++h6) {
            int rowIdx = srow + 32 * h6;          // 0..191
            int g = rowIdx >> 5, jj2 = rowIdx & 31;
            float4 wv = *(const float4*)(Bg + (size_t)(g*128 + j0 + jj2)*128 + k0 + skq);
            Ws[skq+0][rowIdx] = wv.x; Ws[skq+1][rowIdx] = wv.y; Ws[skq+2][rowIdx] = wv.z; Ws[skq+3][rowIdx] = wv.w;
        }
        __syncthreads();
        #pragma unroll
        for (int kk = 0; kk < 32; ++kk) {
            float xa[8], ha[8];
            *(float4*)&xa[0] = *(const float4*)&Xs[kk][rr*8];
            *(float4*)&xa[4] = *(const float4*)&Xs[kk][rr*8+4];
            *(float4*)&ha[0] = *(const float4*)&Hs[kk][rr*8];
            *(float4*)&ha[4] = *(const float4*)&Hs[kk][rr*8+4];
            #pragma unroll
            for (int g = 0; g < 3; ++g) {
                float wv = Ws[kk][g*32 + j];
                #pragma unroll
                for (int i = 0; i < 8; ++i) acc[g][i] = fmaf(xa[i], wv, acc[g][i]);
            }
            #pragma unroll
            for (int g = 3; g < 6; ++g) {
                float wv = Ws[kk][g*32 + j];
                #pragma unroll
                for (int i = 0; i < 8; ++i) acc[g][i] = fmaf(ha[i], wv, acc[g][i]);
            }
        }
        __syncthreads();
    }
    float bi_r = bih[j0 + j], bi_z = bih[128 + j0 + j], bi_n = bih[256 + j0 + j];
    float bh_r = bhh[j0 + j], bh_z = bhh[128 + j0 + j], bh_n = bhh[256 + j0 + j];
    #pragma unroll
    for (int i = 0; i < 8; ++i) {
        int row = m0 + rr*8 + i;
        if (row < M) {
            float r_ = sigmoidf_(acc[0][i] + bi_r + acc[3][i] + bh_r);
            float z_ = sigmoidf_(acc[1][i] + bi_z + acc[4][i] + bh_z);
            float n_ = tanhf_(acc[2][i] + bi_n + r_ * (acc[5][i] + bh_n));
            size_t hi = (size_t)row * 128 + j0 + j;
            Hnew[hi] = (1.f - z_) * n_ + z_ * Hold[hi];
        }
    }
}

// ---------------------------------------------------------------------------
// Fused mean/std+sample+KLD (phi) AND beta+Mt
// ---------------------------------------------------------------------------
__launch_bounds__(256)
__global__ void msmt_kernel(const float* __restrict__ hPhi, const float* __restrict__ hBeta,
                            const float* __restrict__ Bms_n, const float* __restrict__ Bms_c,
                            const float* __restrict__ b_pmean, const float* __restrict__ b_pstd,
                            const float* __restrict__ b_bmean, const float* __restrict__ b_bstd,
                            const float* __restrict__ epsP, const float* __restrict__ epsB,
                            const float* __restrict__ phiPrior, const float* __restrict__ betaPrior,
                            float* __restrict__ phiS, float* __restrict__ betaS,
                            const float* __restrict__ W_dec, float* __restrict__ Mt,
                            float* __restrict__ acc)
{
    __shared__ float red[256];
    int bx = blockIdx.x;
    int tid = threadIdx.x;
    if (bx < 128) {
        __shared__ float Hs[32][64];
        __shared__ float Wms[32][64];
        int m0 = (bx >> 2) * 64, j0 = (bx & 3) * 32;
        int j  = tid & 31;
        int rr = tid >> 5;
        float accM[8] = {}, accS[8] = {};
        int srow = tid >> 3;
        int skq  = (tid & 7) * 4;
        for (int k0 = 0; k0 < 128; k0 += 32) {
            #pragma unroll
            for (int h2 = 0; h2 < 2; ++h2) {
                int row = srow + 32 * h2;
                float4 hv = *(const float4*)(hPhi + (size_t)(m0 + row)*128 + k0 + skq);
                Hs[skq+0][row] = hv.x; Hs[skq+1][row] = hv.y; Hs[skq+2][row] = hv.z; Hs[skq+3][row] = hv.w;
            }
            #pragma unroll
            for (int h2 = 0; h2 < 2; ++h2) {
                int ri = srow + 32 * h2;            // 0..63: mean rows then std rows
                int grp = ri >> 5, jj2 = ri & 31;
                float4 wv = *(const float4*)(Bms_n + (size_t)(grp*128 + j0 + jj2)*128 + k0 + skq);
                Wms[skq+0][ri] = wv.x; Wms[skq+1][ri] = wv.y; Wms[skq+2][ri] = wv.z; Wms[skq+3][ri] = wv.w;
            }
            __syncthreads();
            #pragma unroll
            for (int kk = 0; kk < 32; ++kk) {
                float hv[8];
                *(float4*)&hv[0] = *(const float4*)&Hs[kk][rr*8];
                *(float4*)&hv[4] = *(const float4*)&Hs[kk][rr*8+4];
                float wm = Wms[kk][j];
                float wsv = Wms[kk][32 + j];
                #pragma unroll
                for (int i = 0; i < 8; ++i) {
                    accM[i] = fmaf(hv[i], wm, accM[i]);
                    accS[i] = fmaf(hv[i], wsv, accS[i]);
                }
            }
            __syncthreads();
        }
        float bmv = b_pmean[j0 + j], bsv = b_pstd[j0 + j];
        float kld = 0.f;
        #pragma unroll
        for (int i = 0; i < 8; ++i) {
            int row = m0 + rr*8 + i;
            size_t gi = (size_t)row * 128 + j0 + j;
            float mean = accM[i] + bmv;
            float stdv = softplusf_(accS[i] + bsv);
            phiS[gi] = mean + stdv * epsP[gi];
            float d = mean - phiPrior[gi];
            kld += -logf_(stdv) + 0.5f*(stdv*stdv + d*d) - 0.5f;
        }
        red[tid] = kld; __syncthreads();
        for (int st = 128; st > 0; st >>= 1) { if (tid < st) red[tid] += red[tid + st]; __syncthreads(); }
        if (tid == 0) atomicAdd(acc + 4, red[0]);
    } else {
        __shared__ float hb[2048];        // h_beta 16x128
        __shared__ float sbeta[16*132];   // padded beta_s
        int bm = bx - 128;                // 0..31
        // stage h_beta
        {
            int base = tid * 8;
            *(float4*)&hb[base]     = *(const float4*)(hBeta + base);
            *(float4*)&hb[base + 4] = *(const float4*)(hBeta + base + 4);
        }
        __syncthreads();
        // beta ms: thread (j = tid&127, half = tid>>7) -> 8 rows
        {
            int j = tid & 127, half = tid >> 7;
            float accM[8] = {}, accS[8] = {};
            const float* wmrow = Bms_c + (size_t)j * 128;
            const float* wsrow = Bms_c + (size_t)(128 + j) * 128;
            for (int d4 = 0; d4 < 32; ++d4) {
                float4 wm = *(const float4*)(wmrow + d4*4);
                float4 wsv = *(const float4*)(wsrow + d4*4);
                #pragma unroll
                for (int i = 0; i < 8; ++i) {
                    int r = half*8 + i;
                    float4 hv = *(const float4*)&hb[r*128 + d4*4];
                    accM[i] += D4(hv, wm);
                    accS[i] += D4(hv, wsv);
                }
            }
            float bmv = b_bmean[j], bsv = b_bstd[j];
            float kld = 0.f;
            #pragma unroll
            for (int i = 0; i < 8; ++i) {
                int r = half*8 + i;
                float mean = accM[i] + bmv;
                float stdv = softplusf_(accS[i] + bsv);
                float sv = mean + stdv * epsB[r*128 + j];
                sbeta[r*132 + j] = sv;
                if (bm == 0) {
                    betaS[r*128 + j] = sv;
                    float d = mean - betaPrior[r*128 + j];
                    kld += (-2.3025850929940457f - logf_(stdv)) + 50.0f*(stdv*stdv + d*d) - 0.5f;
                }
            }
            if (bm == 0) {
                red[tid] = kld; __syncthreads();
                for (int st = 128; st > 0; st >>= 1) { if (tid < st) red[tid] += red[tid + st]; __syncthreads(); }
                if (tid == 0) atomicAdd(acc + 3, red[0]);
            }
        }
        __syncthreads();
        // Mt rows bm*64 .. +64
        {
            int w = tid >> 6, l = tid & 63;
            int k = l & 15, q = l >> 4;
            const float* sb = &sbeta[k*132 + q*32];
            #pragma unroll 4
            for (int rr2 = 0; rr2 < 16; ++rr2) {
                int n = bm*64 + w*16 + rr2;
                const float* wd = W_dec + (size_t)n*128 + q*32;
                float p = 0.f;
                #pragma unroll
                for (int i4 = 0; i4 < 8; ++i4) {
                    float4 a = *(const float4*)(sb + i4*4);
                    float4 b = *(const float4*)(wd + i4*4);
                    p += D4(a, b);
                }
                p += __shfl_xor(p, 16);
                p += __shfl_xor(p, 32);
                if (l < 16) Mt[n*16 + l] = p * LOG2E;
            }
        }
    }
}

// ---------------------------------------------------------------------------
// Fused z + nll. 512 blocks x 512 thr, 32 edges/block, launch_bounds(512,2)
// (2 waves/EU min -> VGPR cap 256: NO spill of the 64-float Mt fragment;
// round 6's (512,4) cap spilled it -> 67 MB scratch traffic).
// ---------------------------------------------------------------------------
#define ZSTEP(A,B,Wv,Bv) { float4 a_=(A), b_=(B); \
    lp += a_.x*(Bv).x + a_.y*(Bv).y + a_.z*(Bv).z + a_.w*(Bv).w; \
    lq += (a_.x*b_.x)*(Wv).x + (a_.y*b_.y)*(Wv).y + (a_.z*b_.z)*(Wv).z + (a_.w*b_.w)*(Wv).w; }

__launch_bounds__(512, 2)
__global__ void znll_kernel(const float* __restrict__ phiS, const float* __restrict__ betaS,
                            const float* __restrict__ W_pi, const float* __restrict__ Mt,
                            const int* __restrict__ edges_t, const float* __restrict__ u_t,
                            float* __restrict__ acc)
{
    __shared__ float zbuf[32][16];
    __shared__ int   cbuf[32];
    __shared__ float ss[32][8];
    __shared__ float kred[8], cvred[8];
    int tid = threadIdx.x, wid = tid >> 6, l = tid & 63;
    // ---- phase 1 ----
    {
        int k = l >> 2, q = l & 3;
        int d0 = q * 32;
        const float4* wp = (const float4*)(W_pi  + k*128 + d0);
        const float4* bp = (const float4*)(betaS + k*128 + d0);
        float4 wr0 = wp[0], wr1 = wp[1], wr2 = wp[2], wr3 = wp[3],
               wr4 = wp[4], wr5 = wp[5], wr6 = wp[6], wr7 = wp[7];
        float4 br0 = bp[0], br1 = bp[1], br2 = bp[2], br3 = bp[3],
               br4 = bp[4], br5 = bp[5], br6 = bp[6], br7 = bp[7];
        float kz = 0.f;
        #pragma unroll
        for (int it = 0; it < 4; ++it) {
            int jl = wid * 4 + it;               // 0..31
            int j = blockIdx.x * 32 + jl;        // 0..16383
            int e = j & 8191; int fl = j >> 13;
            int w = edges_t[e*2 + fl], c = edges_t[e*2 + (fl ^ 1)];
            const float4* pw4 = (const float4*)(phiS + (size_t)w*128 + d0);
            const float4* pc4 = (const float4*)(phiS + (size_t)c*128 + d0);
            float lq = 0.f, lp = 0.f;
            ZSTEP(pw4[0], pc4[0], wr0, br0); ZSTEP(pw4[1], pc4[1], wr1, br1);
            ZSTEP(pw4[2], pc4[2], wr2, br2); ZSTEP(pw4[3], pc4[3], wr3, br3);
            ZSTEP(pw4[4], pc4[4], wr4, br4); ZSTEP(pw4[5], pc4[5], wr5, br5);
            ZSTEP(pw4[6], pc4[6], wr6, br6); ZSTEP(pw4[7], pc4[7], wr7, br7);
            lq += __shfl_xor(lq, 1); lq += __shfl_xor(lq, 2);
            lp += __shfl_xor(lp, 1); lp += __shfl_xor(lp, 2);
            // posterior log-softmax (no max: |lq| bounded)
            float eq = expf_(lq);
            float sq = eq;
            sq += __shfl_xor(sq, 4); sq += __shfl_xor(sq, 8); sq += __shfl_xor(sq, 16); sq += __shfl_xor(sq, 32);
            float logpost = lq - logf_(sq);
            float post = eq * __builtin_amdgcn_rcpf(sq);
            // prior log-softmax (keep max)
            float mp = lp;
            mp = fmaxf(mp, __shfl_xor(mp, 4));  mp = fmaxf(mp, __shfl_xor(mp, 8));
            mp = fmaxf(mp, __shfl_xor(mp, 16)); mp = fmaxf(mp, __shfl_xor(mp, 32));
            float ep = expf_(lp - mp);
            float sp = ep;
            sp += __shfl_xor(sp, 4); sp += __shfl_xor(sp, 8); sp += __shfl_xor(sp, 16); sp += __shfl_xor(sp, 32);
            float logprior = (lp - mp) - logf_(sp);
            kz += post * (logpost - logprior);   // this lane's k only (x4 over q)
            // gumbel-softmax sample
            float u = u_t[(size_t)j*16 + k];
            float g = -logf_(-logf_(u + 1e-10f) + 1e-10f);
            float zl = lq + g;
            float ez = expf_(zl);
            float sz = ez;
            sz += __shfl_xor(sz, 4); sz += __shfl_xor(sz, 8); sz += __shfl_xor(sz, 16); sz += __shfl_xor(sz, 32);
            if (q == 0) zbuf[jl][k] = ez * __builtin_amdgcn_rcpf(sz);
            if (l == 0) cbuf[jl] = c;
        }
        #pragma unroll
        for (int m = 1; m < 64; m <<= 1) kz += __shfl_xor(kz, m);
        if (l == 0) kred[wid] = kz * 0.25f;
    }
    __syncthreads();
    // ---- phase 2 ----
    int n0 = tid * 4;
    const float4* mp4 = (const float4*)(Mt + (size_t)n0 * 16);
    float4 M0 = mp4[0],  M1 = mp4[1],  M2 = mp4[2],  M3 = mp4[3];
    float4 M4 = mp4[4],  M5 = mp4[5],  M6 = mp4[6],  M7 = mp4[7];
    float4 M8 = mp4[8],  M9 = mp4[9],  M10 = mp4[10], M11 = mp4[11];
    float4 M12 = mp4[12], M13 = mp4[13], M14 = mp4[14], M15 = mp4[15];
    float cvsum = 0.f;
    #pragma unroll 2
    for (int e = 0; e < 32; ++e) {
        const float4* zp = (const float4*)&zbuf[e][0];
        float4 Z0 = zp[0], Z1 = zp[1], Z2 = zp[2], Z3 = zp[3];
        int c = cbuf[e];
        float v0 = D4(Z0, M0)  + D4(Z1, M1)  + D4(Z2, M2)  + D4(Z3, M3);
        float v1 = D4(Z0, M4)  + D4(Z1, M5)  + D4(Z2, M6)  + D4(Z3, M7);
        float v2 = D4(Z0, M8)  + D4(Z1, M9)  + D4(Z2, M10) + D4(Z3, M11);
        float v3 = D4(Z0, M12) + D4(Z1, M13) + D4(Z2, M14) + D4(Z3, M15);
        float s = exp2_(v0) + exp2_(v1) + exp2_(v2) + exp2_(v3);
        cvsum += (c == n0) ? v0 : 0.f;
        cvsum += (c == n0 + 1) ? v1 : 0.f;
        cvsum += (c == n0 + 2) ? v2 : 0.f;
        cvsum += (c == n0 + 3) ? v3 : 0.f;
        #pragma unroll
        for (int m = 1; m < 64; m <<= 1) s += __shfl_xor(s, m);
        if (l == 0) ss[e][wid] = s;
    }
    #pragma unroll
    for (int m = 1; m < 64; m <<= 1) cvsum += __shfl_xor(cvsum, m);
    if (l == 0) cvred[wid] = cvsum;
    __syncthreads();
    if (wid == 0) {
        float val = 0.f;
        if (l < 32) {
            float S = 0.f;
            #pragma unroll
            for (int w2 = 0; w2 < 8; ++w2) S += ss[l][w2];
            val = log2_(S);
        }
        #pragma unroll
        for (int m = 1; m < 64; m <<= 1) val += __shfl_xor(val, m);
        if (l == 0) {
            float cvt = 0.f, kzt = 0.f;
            #pragma unroll
            for (int w2 = 0; w2 < 8; ++w2) { cvt += cvred[w2]; kzt += kred[w2]; }
            atomicAdd(acc + 0, LN2 * (val - cvt));
            atomicAdd(acc + 1, kzt);
        }
    }
}

__global__ void final_kernel(const float* __restrict__ acc, float* __restrict__ out)
{
    if (threadIdx.x == 0 && blockIdx.x == 0) {
        out[0] = acc[0] / CNT;
        out[1] = acc[1] / CNT;
        out[2] = 16.f * acc[2] / CNT;
        out[3] = acc[3] / CNT;
        out[4] = acc[4] / CNT;
    }
}

// ---------------------------------------------------------------------------
extern "C" void kernel_launch(void* const* d_in, const int* in_sizes, int n_in,
                              void* d_out, int out_size, void* d_ws, size_t ws_size,
                              hipStream_t stream)
{
    (void)in_sizes; (void)n_in; (void)out_size; (void)ws_size;
    const int*   edges   = (const int*)d_in[0];
    const int*   sidx    = (const int*)d_in[1];
    const float* eps_phi = (const float*)d_in[2];
    const float* eps_beta= (const float*)d_in[3];
    const float* u_g     = (const float*)d_in[4];
    const float* amE     = (const float*)d_in[5];
    const float* asE     = (const float*)d_in[6];
    const float* W_s2phi = (const float*)d_in[7];
    const float* b_s2phi = (const float*)d_in[8];
    const float* W_s2beta= (const float*)d_in[9];
    const float* b_s2beta= (const float*)d_in[10];
    const float* W_bmean = (const float*)d_in[11];
    const float* b_bmean = (const float*)d_in[12];
    const float* W_bstd  = (const float*)d_in[13];
    const float* b_bstd  = (const float*)d_in[14];
    const float* W_pmean = (const float*)d_in[15];
    const float* b_pmean = (const float*)d_in[16];
    const float* W_pstd  = (const float*)d_in[17];
    const float* b_pstd  = (const float*)d_in[18];
    const float* W_pi    = (const float*)d_in[19];
    const float* Wih_n   = (const float*)d_in[20];
    const float* Whh_n   = (const float*)d_in[21];
    const float* bih_n   = (const float*)d_in[22];
    const float* bhh_n   = (const float*)d_in[23];
    const float* Wih_c   = (const float*)d_in[24];
    const float* Whh_c   = (const float*)d_in[25];
    const float* bih_c   = (const float*)d_in[26];
    const float* bhh_c   = (const float*)d_in[27];
    const float* W_dec   = (const float*)d_in[28];

    float* ws     = (float*)d_ws;
    float* Bg_n   = ws;                    // 98304
    float* Bg_c   = Bg_n   + 98304;        // 98304
    float* Bms_n  = Bg_c   + 98304;        // 32768
    float* Bms_c  = Bms_n  + 32768;        // 32768
    float* phiA   = Bms_c  + 32768;        // 262144
    float* phiB   = phiA   + 262144;       // 262144
    float* hphiA  = phiB   + 262144;       // 262144
    float* hphiB  = hphiA  + 262144;       // 262144
    float* betaA  = hphiB  + 262144;       // 2048
    float* betaB  = betaA  + 2048;         // 2048
    float* hbetaA = betaB  + 2048;         // 2048
    float* hbetaB = hbetaA + 2048;         // 2048
    float* Mt     = hbetaB + 2048;         // 32768
    float* acc    = Mt     + 32768;        // 8

    init_kernel<<<1025, 256, 0, stream>>>(Wih_n, Whh_n, Wih_c, Whh_c,
                                          W_pmean, W_pstd, W_bmean, W_bstd,
                                          Bg_n, Bg_c, Bms_n, Bms_c,
                                          hphiA, hbetaA, amE, asE, sidx, acc);
    phi0_kernel<<<66048, 256, 0, stream>>>(W_s2phi, b_s2phi, W_s2beta, b_s2beta, amE, sidx, phiA, betaA);

    float* phiPrior = phiA;  float* phiS = phiB;
    float* betaPrior = betaA; float* betaS = betaB;
    float* hPhiOld = hphiA;  float* hPhiNew = hphiB;
    float* hBetaOld = hbetaA; float* hBetaNew = hbetaB;
    for (int t = 0; t < TT; ++t) {
        gru_kernel<<<132, 256, 0, stream>>>(phiPrior, betaPrior,
                                            hPhiOld, hPhiNew, hBetaOld, hBetaNew,
                                            Bg_n, Bg_c, bih_n, bhh_n, bih_c, bhh_c);
        msmt_kernel<<<160, 256, 0, stream>>>(hPhiNew, hBetaNew, Bms_n, Bms_c,
                                             b_pmean, b_pstd, b_bmean, b_bstd,
                                             eps_phi + (size_t)t * 262144, eps_beta + (size_t)t * 2048,
                                             phiPrior, betaPrior, phiS, betaS, W_dec, Mt, acc);
        znll_kernel<<<512, 512, 0, stream>>>(phiS, betaS, W_pi, Mt,
                                             edges + (size_t)t * EE * 2, u_g + (size_t)t * TWOE * KK, acc);
        float* tp = phiPrior; phiPrior = phiS; phiS = tp;
        float* tb = betaPrior; betaPrior = betaS; betaS = tb;
        float* th = hPhiOld; hPhiOld = hPhiNew; hPhiNew = th;
        float* tb2 = hBetaOld; hBetaOld = hBetaNew; hBetaNew = tb2;
    }
    final_kernel<<<1, 64, 0, stream>>>(acc, (float*)d_out);
}

// Round 8
// 2455.445 us; speedup vs baseline: 1.0079x; 1.0063x over previous
//
#include <hip/hip_runtime.h>

// Problem constants
#define NN 2048
#define DD 128
#define KK 16
#define TT 16
#define EE 8192
#define TWOE 16384
#define CNT 262144.0f   // T * 2E

#define LOG2E 1.4426950408889634f
#define LN2   0.6931471805599453f

__device__ __forceinline__ float exp2_(float x) { return __builtin_amdgcn_exp2f(x); }
__device__ __forceinline__ float log2_(float x) { return __builtin_amdgcn_logf(x); }
__device__ __forceinline__ float expf_(float x) { return exp2_(x * LOG2E); }
__device__ __forceinline__ float logf_(float x) { return log2_(x) * LN2; }
__device__ __forceinline__ float sigmoidf_(float x) { return 1.f / (1.f + expf_(-x)); }
__device__ __forceinline__ float softplusf_(float x) { return fmaxf(x, 0.f) + logf_(1.f + expf_(-fabsf(x))); }
__device__ __forceinline__ float tanhf_(float x) { return 1.f - 2.f / (1.f + expf_(2.f * x)); }

#define D4(a,b) ((a).x*(b).x + (a).y*(b).y + (a).z*(b).z + (a).w*(b).w)

// ---------------------------------------------------------------------------
// init: prep concat weights + zero h/acc + alpha kld.
// ---------------------------------------------------------------------------
__launch_bounds__(256)
__global__ void init_kernel(const float* __restrict__ Wih_n, const float* __restrict__ Whh_n,
                            const float* __restrict__ Wih_c, const float* __restrict__ Whh_c,
                            const float* __restrict__ W_pmean, const float* __restrict__ W_pstd,
                            const float* __restrict__ W_bmean, const float* __restrict__ W_bstd,
                            float* __restrict__ Bg_n, float* __restrict__ Bg_c,
                            float* __restrict__ Bms_n, float* __restrict__ Bms_c,
                            float* __restrict__ hphiA, float* __restrict__ hbetaA,
                            const float* __restrict__ amE, const float* __restrict__ asE,
                            const int* __restrict__ sidx, float* __restrict__ acc)
{
    if (blockIdx.x == 1024) {
        __shared__ float red[128];
        int d = threadIdx.x;
        if (d < 128) {
            int s = sidx[0];
            float am = amE[s*128 + d];
            float as = softplusf_(asE[s*128 + d]);
            red[d] = -logf_(as) + 0.5f*(as*as + am*am) - 0.5f;
        }
        __syncthreads();
        for (int st = 64; st > 0; st >>= 1) { if (d < st && d + st < 128) red[d] += red[d + st]; __syncthreads(); }
        if (d == 0) acc[2] = red[0];
        return;
    }
    int idx = blockIdx.x * 256 + threadIdx.x;   // < 262144
    hphiA[idx] = 0.f;
    if (idx < 2048) hbetaA[idx] = 0.f;
    if (idx < 2) { acc[idx] = 0.f; acc[idx + 3] = 0.f; }
    if (idx < 98304) {
        int r = idx;
        if (r < 49152) { int j = r >> 7, k2 = r & 127; Bg_n[r] = Wih_n[j*256 + k2] + Wih_n[j*256 + 128 + k2]; }
        else Bg_n[r] = Whh_n[r - 49152];
    } else if (idx < 196608) {
        int r = idx - 98304;
        if (r < 49152) { int j = r >> 7, k2 = r & 127; Bg_c[r] = Wih_c[j*256 + k2] + Wih_c[j*256 + 128 + k2]; }
        else Bg_c[r] = Whh_c[r - 49152];
    } else if (idx < 229376) {
        int r = idx - 196608;
        Bms_n[r] = (r < 16384) ? W_pmean[r] : W_pstd[r - 16384];
    } else {
        int r = idx - 229376;
        Bms_c[r] = (r < 16384) ? W_bmean[r] : W_bstd[r - 16384];
    }
}

// ---------------------------------------------------------------------------
// phi0/beta0 GEMV
// ---------------------------------------------------------------------------
__launch_bounds__(256)
__global__ void phi0_kernel(const float* __restrict__ Wp, const float* __restrict__ bp,
                            const float* __restrict__ Wb, const float* __restrict__ bb,
                            const float* __restrict__ amE, const int* __restrict__ sidx,
                            float* __restrict__ phi0, float* __restrict__ beta0)
{
    int wid = threadIdx.x >> 6, l = threadIdx.x & 63;
    int s = sidx[0];
    long long row = (long long)blockIdx.x * 4 + wid;     // < 264192
    const float* W; const float* b; float* o; long long r = row;
    if (row < 262144) { W = Wp; b = bp; o = phi0; }
    else { W = Wb; b = bb; o = beta0; r = row - 262144; }
    const float* wr = W + r * 128;
    float acc = amE[s*128 + l] * wr[l] + amE[s*128 + 64 + l] * wr[64 + l];
    #pragma unroll
    for (int m = 32; m >= 1; m >>= 1) acc += __shfl_xor(acc, m);
    if (l == 0) o[r] = acc + b[r];
}

// ---------------------------------------------------------------------------
// Fused GRU
// ---------------------------------------------------------------------------
__launch_bounds__(256)
__global__ void gru_kernel(const float* __restrict__ phiPrior, const float* __restrict__ betaPrior,
                           const float* __restrict__ hPhiOld, float* __restrict__ hPhiNew,
                           const float* __restrict__ hBetaOld, float* __restrict__ hBetaNew,
                           const float* __restrict__ Bg_n, const float* __restrict__ Bg_c,
                           const float* __restrict__ bih_n, const float* __restrict__ bhh_n,
                           const float* __restrict__ bih_c, const float* __restrict__ bhh_c)
{
    __shared__ float Xs[32][64];
    __shared__ float Hs[32][64];
    __shared__ float Ws[32][192];
    int bx = blockIdx.x;
    const float* X; const float* Hold; float* Hnew; const float* Bg; const float* bih; const float* bhh;
    int m0, M, j0;
    if (bx < 128) {
        m0 = (bx >> 2) * 64; j0 = (bx & 3) * 32; M = 2048;
        X = phiPrior; Hold = hPhiOld; Hnew = hPhiNew; Bg = Bg_n; bih = bih_n; bhh = bhh_n;
    } else {
        m0 = 0; j0 = (bx - 128) * 32; M = 16;
        X = betaPrior; Hold = hBetaOld; Hnew = hBetaNew; Bg = Bg_c; bih = bih_c; bhh = bhh_c;
    }
    int tid = threadIdx.x;
    int j  = tid & 31;
    int rr = tid >> 5;            // 0..7 -> rows rr*8..rr*8+7
    float acc[6][8] = {};
    int srow = tid >> 3;          // 0..31
    int skq  = (tid & 7) * 4;
    for (int k0 = 0; k0 < 128; k0 += 32) {
        #pragma unroll
        for (int h2 = 0; h2 < 2; ++h2) {
            int row = srow + 32 * h2;
            int grow = m0 + row;
            float4 xv = make_float4(0.f,0.f,0.f,0.f), hv = xv;
            if (grow < M) {
                xv = *(const float4*)(X    + (size_t)grow*128 + k0 + skq);
                hv = *(const float4*)(Hold + (size_t)grow*128 + k0 + skq);
            }
            Xs[skq+0][row] = xv.x; Xs[skq+1][row] = xv.y; Xs[skq+2][row] = xv.z; Xs[skq+3][row] = xv.w;
            Hs[skq+0][row] = hv.x; Hs[skq+1][row] = hv.y; Hs[skq+2][row] = hv.z; Hs[skq+3][row] = hv.w;
        }
        #pragma unroll
        for (int h6 = 0; h6 < 6; ++h6) {
            int rowIdx = srow + 32 * h6;          // 0..191
            int g = rowIdx >> 5, jj2 = rowIdx & 31;
            float4 wv = *(const float4*)(Bg + (size_t)(g*128 + j0 + jj2)*128 + k0 + skq);
            Ws[skq+0][rowIdx] = wv.x; Ws[skq+1][rowIdx] = wv.y; Ws[skq+2][rowIdx] = wv.z; Ws[skq+3][rowIdx] = wv.w;
        }
        __syncthreads();
        #pragma unroll
        for (int kk = 0; kk < 32; ++kk) {
            float xa[8], ha[8];
            *(float4*)&xa[0] = *(const float4*)&Xs[kk][rr*8];
            *(float4*)&xa[4] = *(const float4*)&Xs[kk][rr*8+4];
            *(float4*)&ha[0] = *(const float4*)&Hs[kk][rr*8];
            *(float4*)&ha[4] = *(const float4*)&Hs[kk][rr*8+4];
            #pragma unroll
            for (int g = 0; g < 3; ++g) {
                float wv = Ws[kk][g*32 + j];
                #pragma unroll
                for (int i = 0; i < 8; ++i) acc[g][i] = fmaf(xa[i], wv, acc[g][i]);
            }
            #pragma unroll
            for (int g = 3; g < 6; ++g) {
                float wv = Ws[kk][g*32 + j];
                #pragma unroll
                for (int i = 0; i < 8; ++i) acc[g][i] = fmaf(ha[i], wv, acc[g][i]);
            }
        }
        __syncthreads();
    }
    float bi_r = bih[j0 + j], bi_z = bih[128 + j0 + j], bi_n = bih[256 + j0 + j];
    float bh_r = bhh[j0 + j], bh_z = bhh[128 + j0 + j], bh_n = bhh[256 + j0 + j];
    #pragma unroll
    for (int i = 0; i < 8; ++i) {
        int row = m0 + rr*8 + i;
        if (row < M) {
            float r_ = sigmoidf_(acc[0][i] + bi_r + acc[3][i] + bh_r);
            float z_ = sigmoidf_(acc[1][i] + bi_z + acc[4][i] + bh_z);
            float n_ = tanhf_(acc[2][i] + bi_n + r_ * (acc[5][i] + bh_n));
            size_t hi = (size_t)row * 128 + j0 + j;
            Hnew[hi] = (1.f - z_) * n_ + z_ * Hold[hi];
        }
    }
}

// ---------------------------------------------------------------------------
// Fused mean/std+sample+KLD (phi) AND beta+Mt
// ---------------------------------------------------------------------------
__launch_bounds__(256)
__global__ void msmt_kernel(const float* __restrict__ hPhi, const float* __restrict__ hBeta,
                            const float* __restrict__ Bms_n, const float* __restrict__ Bms_c,
                            const float* __restrict__ b_pmean, const float* __restrict__ b_pstd,
                            const float* __restrict__ b_bmean, const float* __restrict__ b_bstd,
                            const float* __restrict__ epsP, const float* __restrict__ epsB,
                            const float* __restrict__ phiPrior, const float* __restrict__ betaPrior,
                            float* __restrict__ phiS, float* __restrict__ betaS,
                            const float* __restrict__ W_dec, float* __restrict__ Mt,
                            float* __restrict__ acc)
{
    __shared__ float red[256];
    int bx = blockIdx.x;
    int tid = threadIdx.x;
    if (bx < 128) {
        __shared__ float Hs[32][64];
        __shared__ float Wms[32][64];
        int m0 = (bx >> 2) * 64, j0 = (bx & 3) * 32;
        int j  = tid & 31;
        int rr = tid >> 5;
        float accM[8] = {}, accS[8] = {};
        int srow = tid >> 3;
        int skq  = (tid & 7) * 4;
        for (int k0 = 0; k0 < 128; k0 += 32) {
            #pragma unroll
            for (int h2 = 0; h2 < 2; ++h2) {
                int row = srow + 32 * h2;
                float4 hv = *(const float4*)(hPhi + (size_t)(m0 + row)*128 + k0 + skq);
                Hs[skq+0][row] = hv.x; Hs[skq+1][row] = hv.y; Hs[skq+2][row] = hv.z; Hs[skq+3][row] = hv.w;
            }
            #pragma unroll
            for (int h2 = 0; h2 < 2; ++h2) {
                int ri = srow + 32 * h2;            // 0..63: mean rows then std rows
                int grp = ri >> 5, jj2 = ri & 31;
                float4 wv = *(const float4*)(Bms_n + (size_t)(grp*128 + j0 + jj2)*128 + k0 + skq);
                Wms[skq+0][ri] = wv.x; Wms[skq+1][ri] = wv.y; Wms[skq+2][ri] = wv.z; Wms[skq+3][ri] = wv.w;
            }
            __syncthreads();
            #pragma unroll
            for (int kk = 0; kk < 32; ++kk) {
                float hv[8];
                *(float4*)&hv[0] = *(const float4*)&Hs[kk][rr*8];
                *(float4*)&hv[4] = *(const float4*)&Hs[kk][rr*8+4];
                float wm = Wms[kk][j];
                float wsv = Wms[kk][32 + j];
                #pragma unroll
                for (int i = 0; i < 8; ++i) {
                    accM[i] = fmaf(hv[i], wm, accM[i]);
                    accS[i] = fmaf(hv[i], wsv, accS[i]);
                }
            }
            __syncthreads();
        }
        float bmv = b_pmean[j0 + j], bsv = b_pstd[j0 + j];
        float kld = 0.f;
        #pragma unroll
        for (int i = 0; i < 8; ++i) {
            int row = m0 + rr*8 + i;
            size_t gi = (size_t)row * 128 + j0 + j;
            float mean = accM[i] + bmv;
            float stdv = softplusf_(accS[i] + bsv);
            phiS[gi] = mean + stdv * epsP[gi];
            float d = mean - phiPrior[gi];
            kld += -logf_(stdv) + 0.5f*(stdv*stdv + d*d) - 0.5f;
        }
        red[tid] = kld; __syncthreads();
        for (int st = 128; st > 0; st >>= 1) { if (tid < st) red[tid] += red[tid + st]; __syncthreads(); }
        if (tid == 0) atomicAdd(acc + 4, red[0]);
    } else {
        __shared__ float hb[2048];        // h_beta 16x128
        __shared__ float sbeta[16*132];   // padded beta_s
        int bm = bx - 128;                // 0..31
        {
            int base = tid * 8;
            *(float4*)&hb[base]     = *(const float4*)(hBeta + base);
            *(float4*)&hb[base + 4] = *(const float4*)(hBeta + base + 4);
        }
        __syncthreads();
        {
            int j = tid & 127, half = tid >> 7;
            float accM[8] = {}, accS[8] = {};
            const float* wmrow = Bms_c + (size_t)j * 128;
            const float* wsrow = Bms_c + (size_t)(128 + j) * 128;
            for (int d4 = 0; d4 < 32; ++d4) {
                float4 wm = *(const float4*)(wmrow + d4*4);
                float4 wsv = *(const float4*)(wsrow + d4*4);
                #pragma unroll
                for (int i = 0; i < 8; ++i) {
                    int r = half*8 + i;
                    float4 hv = *(const float4*)&hb[r*128 + d4*4];
                    accM[i] += D4(hv, wm);
                    accS[i] += D4(hv, wsv);
                }
            }
            float bmv = b_bmean[j], bsv = b_bstd[j];
            float kld = 0.f;
            #pragma unroll
            for (int i = 0; i < 8; ++i) {
                int r = half*8 + i;
                float mean = accM[i] + bmv;
                float stdv = softplusf_(accS[i] + bsv);
                float sv = mean + stdv * epsB[r*128 + j];
                sbeta[r*132 + j] = sv;
                if (bm == 0) {
                    betaS[r*128 + j] = sv;
                    float d = mean - betaPrior[r*128 + j];
                    kld += (-2.3025850929940457f - logf_(stdv)) + 50.0f*(stdv*stdv + d*d) - 0.5f;
                }
            }
            if (bm == 0) {
                red[tid] = kld; __syncthreads();
                for (int st = 128; st > 0; st >>= 1) { if (tid < st) red[tid] += red[tid + st]; __syncthreads(); }
                if (tid == 0) atomicAdd(acc + 3, red[0]);
            }
        }
        __syncthreads();
        {
            int w = tid >> 6, l = tid & 63;
            int k = l & 15, q = l >> 4;
            const float* sb = &sbeta[k*132 + q*32];
            #pragma unroll 4
            for (int rr2 = 0; rr2 < 16; ++rr2) {
                int n = bm*64 + w*16 + rr2;
                const float* wd = W_dec + (size_t)n*128 + q*32;
                float p = 0.f;
                #pragma unroll
                for (int i4 = 0; i4 < 8; ++i4) {
                    float4 a = *(const float4*)(sb + i4*4);
                    float4 b = *(const float4*)(wd + i4*4);
                    p += D4(a, b);
                }
                p += __shfl_xor(p, 16);
                p += __shfl_xor(p, 32);
                if (l < 16) Mt[n*16 + l] = p * LOG2E;
            }
        }
    }
}

// ---------------------------------------------------------------------------
// z kernel: 1024 blocks x 256 thr, launch_bounds(256,3) -> 3 blocks/CU =
// 12 waves/CU (znll's 8-wave residency was the latency bottleneck).
// Wave handles 4 edges; lane (k=l>>2, q=l&3).
// ---------------------------------------------------------------------------
#define ZSTEP(A,B,Wv,Bv) { float4 a_=(A), b_=(B); \
    lp += a_.x*(Bv).x + a_.y*(Bv).y + a_.z*(Bv).z + a_.w*(Bv).w; \
    lq += (a_.x*b_.x)*(Wv).x + (a_.y*b_.y)*(Wv).y + (a_.z*b_.z)*(Wv).z + (a_.w*b_.w)*(Wv).w; }

__launch_bounds__(256, 3)
__global__ void z_kernel(const float* __restrict__ phiS, const float* __restrict__ betaS,
                         const float* __restrict__ W_pi, const int* __restrict__ edges_t,
                         const float* __restrict__ u_t, float* __restrict__ Z,
                         float* __restrict__ acc)
{
    __shared__ float kred[4];
    int tid = threadIdx.x, wid = tid >> 6, l = tid & 63;
    int k = l >> 2, q = l & 3;
    int d0 = q * 32;
    const float4* wp = (const float4*)(W_pi  + k*128 + d0);
    const float4* bp = (const float4*)(betaS + k*128 + d0);
    float4 wr0 = wp[0], wr1 = wp[1], wr2 = wp[2], wr3 = wp[3],
           wr4 = wp[4], wr5 = wp[5], wr6 = wp[6], wr7 = wp[7];
    float4 br0 = bp[0], br1 = bp[1], br2 = bp[2], br3 = bp[3],
           br4 = bp[4], br5 = bp[5], br6 = bp[6], br7 = bp[7];
    float kz = 0.f;
    int gw = blockIdx.x * 4 + wid;          // 0..4095
    #pragma unroll
    for (int it = 0; it < 4; ++it) {
        int j = gw * 4 + it;                // 0..16383
        int e = j & 8191; int fl = j >> 13;
        int w = edges_t[e*2 + fl], c = edges_t[e*2 + (fl ^ 1)];
        const float4* pw4 = (const float4*)(phiS + (size_t)w*128 + d0);
        const float4* pc4 = (const float4*)(phiS + (size_t)c*128 + d0);
        float lq = 0.f, lp = 0.f;
        ZSTEP(pw4[0], pc4[0], wr0, br0); ZSTEP(pw4[1], pc4[1], wr1, br1);
        ZSTEP(pw4[2], pc4[2], wr2, br2); ZSTEP(pw4[3], pc4[3], wr3, br3);
        ZSTEP(pw4[4], pc4[4], wr4, br4); ZSTEP(pw4[5], pc4[5], wr5, br5);
        ZSTEP(pw4[6], pc4[6], wr6, br6); ZSTEP(pw4[7], pc4[7], wr7, br7);
        lq += __shfl_xor(lq, 1); lq += __shfl_xor(lq, 2);
        lp += __shfl_xor(lp, 1); lp += __shfl_xor(lp, 2);
        // posterior log-softmax (no max: |lq| bounded)
        float eq = expf_(lq);
        float sq = eq;
        sq += __shfl_xor(sq, 4); sq += __shfl_xor(sq, 8); sq += __shfl_xor(sq, 16); sq += __shfl_xor(sq, 32);
        float logpost = lq - logf_(sq);
        float post = eq * __builtin_amdgcn_rcpf(sq);
        // prior log-softmax (keep max)
        float mp = lp;
        mp = fmaxf(mp, __shfl_xor(mp, 4));  mp = fmaxf(mp, __shfl_xor(mp, 8));
        mp = fmaxf(mp, __shfl_xor(mp, 16)); mp = fmaxf(mp, __shfl_xor(mp, 32));
        float ep = expf_(lp - mp);
        float sp = ep;
        sp += __shfl_xor(sp, 4); sp += __shfl_xor(sp, 8); sp += __shfl_xor(sp, 16); sp += __shfl_xor(sp, 32);
        float logprior = (lp - mp) - logf_(sp);
        kz += post * (logpost - logprior);   // this lane's k only (x4 over q)
        // gumbel-softmax sample
        float u = u_t[(size_t)j*16 + k];
        float g = -logf_(-logf_(u + 1e-10f) + 1e-10f);
        float zl = lq + g;
        float ez = expf_(zl);
        float sz = ez;
        sz += __shfl_xor(sz, 4); sz += __shfl_xor(sz, 8); sz += __shfl_xor(sz, 16); sz += __shfl_xor(sz, 32);
        if (q == 0) Z[(size_t)j*16 + k] = ez * __builtin_amdgcn_rcpf(sz);
    }
    #pragma unroll
    for (int m = 1; m < 64; m <<= 1) kz += __shfl_xor(kz, m);
    if (l == 0) kred[wid] = kz * 0.25f;
    __syncthreads();
    if (tid == 0) atomicAdd(acc + 1, kred[0] + kred[1] + kred[2] + kred[3]);
}

// ---------------------------------------------------------------------------
// nll kernel: 256 blocks x 512 thr (one residency round at 1 block/CU),
// 64 edges/block. Mt fragment in registers (launch_bounds(512,2): VGPR cap
// 256, no spill — (512,4) spilled in round 6). Z tile staged to LDS.
// ---------------------------------------------------------------------------
__launch_bounds__(512, 2)
__global__ void nll_kernel(const float* __restrict__ Mt, const float* __restrict__ Z,
                           const int* __restrict__ edges_t, float* __restrict__ acc)
{
    __shared__ float zs[64][16];
    __shared__ int   cbuf[64];
    __shared__ float ss[64][8];
    __shared__ float cvred[8];
    int tid = threadIdx.x, wid = tid >> 6, l = tid & 63;
    int j0 = blockIdx.x * 64;
    if (tid < 256) {
        int e = tid >> 2, f4 = tid & 3;
        *(float4*)&zs[e][f4*4] = *(const float4*)(Z + (size_t)(j0 + e)*16 + f4*4);
    }
    if (tid >= 256 && tid < 320) {
        int jl = tid - 256;
        int j = j0 + jl;
        int e = j & 8191; int fl = j >> 13;
        cbuf[jl] = edges_t[e*2 + (fl ^ 1)];
    }
    int n0 = tid * 4;
    const float4* mp4 = (const float4*)(Mt + (size_t)n0 * 16);
    float4 M0 = mp4[0],  M1 = mp4[1],  M2 = mp4[2],  M3 = mp4[3];
    float4 M4 = mp4[4],  M5 = mp4[5],  M6 = mp4[6],  M7 = mp4[7];
    float4 M8 = mp4[8],  M9 = mp4[9],  M10 = mp4[10], M11 = mp4[11];
    float4 M12 = mp4[12], M13 = mp4[13], M14 = mp4[14], M15 = mp4[15];
    __syncthreads();
    float cvsum = 0.f;
    #pragma unroll 2
    for (int e = 0; e < 64; ++e) {
        const float4* zp = (const float4*)&zs[e][0];
        float4 Z0 = zp[0], Z1 = zp[1], Z2 = zp[2], Z3 = zp[3];
        int c = cbuf[e];
        float v0 = D4(Z0, M0)  + D4(Z1, M1)  + D4(Z2, M2)  + D4(Z3, M3);
        float v1 = D4(Z0, M4)  + D4(Z1, M5)  + D4(Z2, M6)  + D4(Z3, M7);
        float v2 = D4(Z0, M8)  + D4(Z1, M9)  + D4(Z2, M10) + D4(Z3, M11);
        float v3 = D4(Z0, M12) + D4(Z1, M13) + D4(Z2, M14) + D4(Z3, M15);
        float s = exp2_(v0) + exp2_(v1) + exp2_(v2) + exp2_(v3);
        cvsum += (c == n0) ? v0 : 0.f;
        cvsum += (c == n0 + 1) ? v1 : 0.f;
        cvsum += (c == n0 + 2) ? v2 : 0.f;
        cvsum += (c == n0 + 3) ? v3 : 0.f;
        #pragma unroll
        for (int m = 1; m < 64; m <<= 1) s += __shfl_xor(s, m);
        if (l == 0) ss[e][wid] = s;
    }
    #pragma unroll
    for (int m = 1; m < 64; m <<= 1) cvsum += __shfl_xor(cvsum, m);
    if (l == 0) cvred[wid] = cvsum;
    __syncthreads();
    if (wid == 0) {
        float S = 0.f;
        #pragma unroll
        for (int w2 = 0; w2 < 8; ++w2) S += ss[l][w2];
        float val = log2_(S);
        #pragma unroll
        for (int m = 1; m < 64; m <<= 1) val += __shfl_xor(val, m);
        if (l == 0) {
            float cvt = 0.f;
            #pragma unroll
            for (int w2 = 0; w2 < 8; ++w2) cvt += cvred[w2];
            atomicAdd(acc + 0, LN2 * (val - cvt));
        }
    }
}

__global__ void final_kernel(const float* __restrict__ acc, float* __restrict__ out)
{
    if (threadIdx.x == 0 && blockIdx.x == 0) {
        out[0] = acc[0] / CNT;
        out[1] = acc[1] / CNT;
        out[2] = 16.f * acc[2] / CNT;
        out[3] = acc[3] / CNT;
        out[4] = acc[4] / CNT;
    }
}

// ---------------------------------------------------------------------------
extern "C" void kernel_launch(void* const* d_in, const int* in_sizes, int n_in,
                              void* d_out, int out_size, void* d_ws, size_t ws_size,
                              hipStream_t stream)
{
    (void)in_sizes; (void)n_in; (void)out_size; (void)ws_size;
    const int*   edges   = (const int*)d_in[0];
    const int*   sidx    = (const int*)d_in[1];
    const float* eps_phi = (const float*)d_in[2];
    const float* eps_beta= (const float*)d_in[3];
    const float* u_g     = (const float*)d_in[4];
    const float* amE     = (const float*)d_in[5];
    const float* asE     = (const float*)d_in[6];
    const float* W_s2phi = (const float*)d_in[7];
    const float* b_s2phi = (const float*)d_in[8];
    const float* W_s2beta= (const float*)d_in[9];
    const float* b_s2beta= (const float*)d_in[10];
    const float* W_bmean = (const float*)d_in[11];
    const float* b_bmean = (const float*)d_in[12];
    const float* W_bstd  = (const float*)d_in[13];
    const float* b_bstd  = (const float*)d_in[14];
    const float* W_pmean = (const float*)d_in[15];
    const float* b_pmean = (const float*)d_in[16];
    const float* W_pstd  = (const float*)d_in[17];
    const float* b_pstd  = (const float*)d_in[18];
    const float* W_pi    = (const float*)d_in[19];
    const float* Wih_n   = (const float*)d_in[20];
    const float* Whh_n   = (const float*)d_in[21];
    const float* bih_n   = (const float*)d_in[22];
    const float* bhh_n   = (const float*)d_in[23];
    const float* Wih_c   = (const float*)d_in[24];
    const float* Whh_c   = (const float*)d_in[25];
    const float* bih_c   = (const float*)d_in[26];
    const float* bhh_c   = (const float*)d_in[27];
    const float* W_dec   = (const float*)d_in[28];

    float* ws     = (float*)d_ws;
    float* Bg_n   = ws;                    // 98304
    float* Bg_c   = Bg_n   + 98304;        // 98304
    float* Bms_n  = Bg_c   + 98304;        // 32768
    float* Bms_c  = Bms_n  + 32768;        // 32768
    float* phiA   = Bms_c  + 32768;        // 262144
    float* phiB   = phiA   + 262144;       // 262144
    float* hphiA  = phiB   + 262144;       // 262144
    float* hphiB  = hphiA  + 262144;       // 262144
    float* betaA  = hphiB  + 262144;       // 2048
    float* betaB  = betaA  + 2048;         // 2048
    float* hbetaA = betaB  + 2048;         // 2048
    float* hbetaB = hbetaA + 2048;         // 2048
    float* Mt     = hbetaB + 2048;         // 32768
    float* Zb     = Mt     + 32768;        // 262144
    float* acc    = Zb     + 262144;       // 8

    init_kernel<<<1025, 256, 0, stream>>>(Wih_n, Whh_n, Wih_c, Whh_c,
                                          W_pmean, W_pstd, W_bmean, W_bstd,
                                          Bg_n, Bg_c, Bms_n, Bms_c,
                                          hphiA, hbetaA, amE, asE, sidx, acc);
    phi0_kernel<<<66048, 256, 0, stream>>>(W_s2phi, b_s2phi, W_s2beta, b_s2beta, amE, sidx, phiA, betaA);

    float* phiPrior = phiA;  float* phiS = phiB;
    float* betaPrior = betaA; float* betaS = betaB;
    float* hPhiOld = hphiA;  float* hPhiNew = hphiB;
    float* hBetaOld = hbetaA; float* hBetaNew = hbetaB;
    for (int t = 0; t < TT; ++t) {
        gru_kernel<<<132, 256, 0, stream>>>(phiPrior, betaPrior,
                                            hPhiOld, hPhiNew, hBetaOld, hBetaNew,
                                            Bg_n, Bg_c, bih_n, bhh_n, bih_c, bhh_c);
        msmt_kernel<<<160, 256, 0, stream>>>(hPhiNew, hBetaNew, Bms_n, Bms_c,
                                             b_pmean, b_pstd, b_bmean, b_bstd,
                                             eps_phi + (size_t)t * 262144, eps_beta + (size_t)t * 2048,
                                             phiPrior, betaPrior, phiS, betaS, W_dec, Mt, acc);
        z_kernel<<<1024, 256, 0, stream>>>(phiS, betaS, W_pi,
                                           edges + (size_t)t * EE * 2, u_g + (size_t)t * TWOE * KK, Zb, acc);
        nll_kernel<<<256, 512, 0, stream>>>(Mt, Zb, edges + (size_t)t * EE * 2, acc);
        float* tp = phiPrior; phiPrior = phiS; phiS = tp;
        float* tb = betaPrior; betaPrior = betaS; betaS = tb;
        float* th = hPhiOld; hPhiOld = hPhiNew; hPhiNew = th;
        float* tb2 = hBetaOld; hBetaOld = hBetaNew; hBetaNew = tb2;
    }
    final_kernel<<<1, 64, 0, stream>>>(acc, (float*)d_out);
}